// Round 1
// baseline (4389.443 us; speedup 1.0000x reference)
//
#include <hip/hip_runtime.h>

// MSDeformAttn pixel decoder, 6-layer encoder. fp32 reference-faithful v0.
// D=256, NH=8, DH=32, NL=3, NP=4, DFF=1024, B=4, Q=5376, M=B*Q=21504.

#define DMODEL 256
#define NHEAD 8
#define DHEAD 32
#define NLVL 3
#define NPNT 4
#define NLAYERS 6
#define DFF 1024
#define BATCH 4
#define QTOT 5376
#define MROWS (BATCH * QTOT)   // 21504, multiple of 64

// ---------------------------------------------------------------------------
// Flatten: src [B,D,H,W] -> x [B,Q,D]; pos + level_embed -> pos [B,Q,D]
// ---------------------------------------------------------------------------
__global__ __launch_bounds__(256) void flatten_kernel(
    const float* __restrict__ s0, const float* __restrict__ p0,
    const float* __restrict__ s1, const float* __restrict__ p1,
    const float* __restrict__ s2, const float* __restrict__ p2,
    const float* __restrict__ lvl, float* __restrict__ x,
    float* __restrict__ pos) {
  int bq = blockIdx.x;               // 0..M-1
  int b = bq / QTOT, q = bq % QTOT;
  int d = threadIdx.x;               // 0..255
  const float* sp; const float* pp; int l, p, hw;
  if (q < 4096)      { l = 0; p = q;        hw = 4096; sp = s0; pp = p0; }
  else if (q < 5120) { l = 1; p = q - 4096; hw = 1024; sp = s1; pp = p1; }
  else               { l = 2; p = q - 5120; hw = 256;  sp = s2; pp = p2; }
  size_t si = ((size_t)(b * DMODEL + d)) * hw + p;
  x[(size_t)bq * DMODEL + d] = sp[si];
  pos[(size_t)bq * DMODEL + d] = pp[si] + lvl[l * DMODEL + d];
}

// ---------------------------------------------------------------------------
// Generic fp32 GEMM: C[M,N] = (A (+A2)) @ W[K,N] + bias, optional ReLU.
// M == MROWS (multiple of 64). Block tile 64x64, BK=16, 256 thr, 4x4/thread.
// ---------------------------------------------------------------------------
__global__ __launch_bounds__(256) void gemm_kernel(
    const float* __restrict__ A, const float* __restrict__ A2,
    const float* __restrict__ W, const float* __restrict__ bias,
    float* __restrict__ C, int N, int K, int relu) {
  __shared__ float As[16][68];   // [k][m], padded
  __shared__ float Bs[16][64];   // [k][n]
  int t = threadIdx.x;
  int tx = t & 15, ty = t >> 4;
  int bm = blockIdx.y, bn = blockIdx.x;

  int arow = t >> 2, ac4 = t & 3;          // A: 64 rows x 4 float4-cols
  int wrow = t >> 4, wc4 = t & 15;         // W: 16 rows x 16 float4-cols
  const float* Aab = A + (size_t)(bm * 64 + arow) * K + ac4 * 4;
  const float* A2b = A2 ? A2 + (size_t)(bm * 64 + arow) * K + ac4 * 4 : nullptr;
  int wcol = bn * 64 + wc4 * 4;

  float acc[4][4];
#pragma unroll
  for (int i = 0; i < 4; ++i)
#pragma unroll
    for (int j = 0; j < 4; ++j) acc[i][j] = 0.f;

  for (int k0 = 0; k0 < K; k0 += 16) {
    float4 a = *(const float4*)(Aab + k0);
    if (A2b) {
      float4 a2 = *(const float4*)(A2b + k0);
      a.x += a2.x; a.y += a2.y; a.z += a2.z; a.w += a2.w;
    }
    float4 wv = make_float4(0.f, 0.f, 0.f, 0.f);
    if (wcol < N) wv = *(const float4*)(W + (size_t)(k0 + wrow) * N + wcol);
    __syncthreads();
    As[ac4 * 4 + 0][arow] = a.x;
    As[ac4 * 4 + 1][arow] = a.y;
    As[ac4 * 4 + 2][arow] = a.z;
    As[ac4 * 4 + 3][arow] = a.w;
    *(float4*)&Bs[wrow][wc4 * 4] = wv;
    __syncthreads();
#pragma unroll
    for (int kk = 0; kk < 16; ++kk) {
      float4 av = *(const float4*)&As[kk][ty * 4];
      float4 bv = *(const float4*)&Bs[kk][tx * 4];
      float aa[4] = {av.x, av.y, av.z, av.w};
      float bb[4] = {bv.x, bv.y, bv.z, bv.w};
#pragma unroll
      for (int ii = 0; ii < 4; ++ii)
#pragma unroll
        for (int jj = 0; jj < 4; ++jj)
          acc[ii][jj] = fmaf(aa[ii], bb[jj], acc[ii][jj]);
    }
  }

#pragma unroll
  for (int ii = 0; ii < 4; ++ii) {
    int row = bm * 64 + ty * 4 + ii;
#pragma unroll
    for (int jj = 0; jj < 4; ++jj) {
      int col = bn * 64 + tx * 4 + jj;
      if (col < N) {
        float v = acc[ii][jj] + bias[col];
        if (relu) v = fmaxf(v, 0.f);
        C[(size_t)row * N + col] = v;
      }
    }
  }
}

// ---------------------------------------------------------------------------
// Deformable sampling + per-head softmax.
// One block per (b,q); thread t: head = t>>5, d = t&31.
// ---------------------------------------------------------------------------
__global__ __launch_bounds__(256) void deform_kernel(
    const float* __restrict__ val, const float* __restrict__ logits,
    const float* __restrict__ off, float* __restrict__ out) {
  int bq = blockIdx.x;
  int b = bq / QTOT, q = bq % QTOT;
  int t = threadIdx.x;
  int hid = t >> 5, d = t & 31;

  int p, wsrc;
  if (q < 4096)      { p = q;        wsrc = 64; }
  else if (q < 5120) { p = q - 4096; wsrc = 32; }
  else               { p = q - 5120; wsrc = 16; }
  float inv = 1.0f / (float)wsrc;
  float refx = ((float)(p % wsrc) + 0.5f) * inv;
  float refy = ((float)(p / wsrc) + 0.5f) * inv;

  // softmax over 12 (NL*NP) logits for this head
  const float* lg = logits + (size_t)bq * 96 + hid * 12;
  float aw[12];
  float mx = -1e30f;
#pragma unroll
  for (int k = 0; k < 12; ++k) { aw[k] = lg[k]; mx = fmaxf(mx, aw[k]); }
  float s = 0.f;
#pragma unroll
  for (int k = 0; k < 12; ++k) { aw[k] = expf(aw[k] - mx); s += aw[k]; }
  float invs = 1.0f / s;

  const float* ob = off + (size_t)bq * 192 + hid * 24;

  const int starts[3] = {0, 4096, 5120};
  const int wls[3] = {64, 32, 16};
  float acc = 0.f;
#pragma unroll
  for (int l = 0; l < 3; ++l) {
    int wl = wls[l], start = starts[l];
    float fwl = (float)wl;
#pragma unroll
    for (int pp = 0; pp < 4; ++pp) {
      float ox = ob[(l * 4 + pp) * 2 + 0];
      float oy = ob[(l * 4 + pp) * 2 + 1];
      float fx = refx * fwl + ox - 0.5f;
      float fy = refy * fwl + oy - 0.5f;
      float x0f = floorf(fx), y0f = floorf(fy);
      float lx = fx - x0f, ly = fy - y0f;
      int x0 = (int)x0f, y0 = (int)y0f;
      float smp = 0.f;
#pragma unroll
      for (int c = 0; c < 4; ++c) {
        int dx = c & 1, dy = c >> 1;
        int xi = x0 + dx, yi = y0 + dy;
        float wgt = (dx ? lx : 1.f - lx) * (dy ? ly : 1.f - ly);
        if (xi >= 0 && xi < wl && yi >= 0 && yi < wl) {
          int idx = yi * wl + xi;
          smp += wgt * val[((size_t)(b * QTOT + start + idx)) * DMODEL + hid * 32 + d];
        }
      }
      acc += aw[l * 4 + pp] * invs * smp;
    }
  }
  out[(size_t)bq * DMODEL + t] = acc;
}

// ---------------------------------------------------------------------------
// x = LayerNorm(x + res) * g + b   (one wave per 256-elem row)
// ---------------------------------------------------------------------------
__global__ __launch_bounds__(256) void add_ln_kernel(
    float* __restrict__ x, const float* __restrict__ res,
    const float* __restrict__ g, const float* __restrict__ bta) {
  int row = blockIdx.x * 4 + (threadIdx.x >> 6);
  int lane = threadIdx.x & 63;
  float4 xv = ((const float4*)(x + (size_t)row * DMODEL))[lane];
  float4 rv = ((const float4*)(res + (size_t)row * DMODEL))[lane];
  xv.x += rv.x; xv.y += rv.y; xv.z += rv.z; xv.w += rv.w;
  float s = xv.x + xv.y + xv.z + xv.w;
  float sq = xv.x * xv.x + xv.y * xv.y + xv.z * xv.z + xv.w * xv.w;
#pragma unroll
  for (int o = 32; o >= 1; o >>= 1) {
    s += __shfl_xor(s, o);
    sq += __shfl_xor(sq, o);
  }
  float mean = s * (1.f / 256.f);
  float var = sq * (1.f / 256.f) - mean * mean;
  float rstd = rsqrtf(var + 1e-5f);
  int c = lane * 4;
  float4 gv = *(const float4*)(g + c);
  float4 bv = *(const float4*)(bta + c);
  float4 o4;
  o4.x = (xv.x - mean) * rstd * gv.x + bv.x;
  o4.y = (xv.y - mean) * rstd * gv.y + bv.y;
  o4.z = (xv.z - mean) * rstd * gv.z + bv.z;
  o4.w = (xv.w - mean) * rstd * gv.w + bv.w;
  ((float4*)(x + (size_t)row * DMODEL))[lane] = o4;
}

// ---------------------------------------------------------------------------
extern "C" void kernel_launch(void* const* d_in, const int* in_sizes, int n_in,
                              void* d_out, int out_size, void* d_ws, size_t ws_size,
                              hipStream_t stream) {
  const float* src0 = (const float*)d_in[0];
  const float* pos0 = (const float*)d_in[1];
  const float* src1 = (const float*)d_in[2];
  const float* pos1 = (const float*)d_in[3];
  const float* src2 = (const float*)d_in[4];
  const float* pos2 = (const float*)d_in[5];
  const float* lvl  = (const float*)d_in[6];
  const float* W_off  = (const float*)d_in[7];
  const float* b_off  = (const float*)d_in[8];
  const float* W_attn = (const float*)d_in[9];
  const float* b_attn = (const float*)d_in[10];
  const float* W_val  = (const float*)d_in[11];
  const float* b_val  = (const float*)d_in[12];
  const float* W_out  = (const float*)d_in[13];
  const float* b_out  = (const float*)d_in[14];
  const float* ln1g = (const float*)d_in[15];
  const float* ln1b = (const float*)d_in[16];
  const float* W_ff1 = (const float*)d_in[17];
  const float* b_ff1 = (const float*)d_in[18];
  const float* W_ff2 = (const float*)d_in[19];
  const float* b_ff2 = (const float*)d_in[20];
  const float* ln2g = (const float*)d_in[21];
  const float* ln2b = (const float*)d_in[22];

  const size_t Msz = (size_t)MROWS;
  float* ws = (float*)d_ws;
  // float-unit offsets (aliasing: proj->val, ffres->off+logits region)
  float* x    = ws;                           // 256*M
  float* pos  = ws + Msz * 256;               // 256*M
  float* val  = ws + Msz * 512;               // 256*M (reused as proj)
  float* offb = ws + Msz * 768;               // 192*M (reused as ffres: 256*M, spills into logits)
  float* lgt  = ws + Msz * 768 + Msz * 192;   // 96*M
  float* attn = ws + Msz * 1056;              // 256*M
  float* ffh  = ws + Msz * 1312;              // 1024*M
  float* proj = val;
  float* ffres = offb;
  // total: 2336*M floats ~ 201 MB

  flatten_kernel<<<MROWS, 256, 0, stream>>>(src0, pos0, src1, pos1, src2, pos2,
                                            lvl, x, pos);

  const int MT = MROWS / 64;  // 336
  for (int i = 0; i < NLAYERS; ++i) {
    // off = (x+pos) @ W_off + b_off          [M,192]
    gemm_kernel<<<dim3(3, MT), 256, 0, stream>>>(
        x, pos, W_off + (size_t)i * 256 * 192, b_off + i * 192, offb, 192, 256, 0);
    // logits = (x+pos) @ W_attn + b_attn     [M,96]
    gemm_kernel<<<dim3(2, MT), 256, 0, stream>>>(
        x, pos, W_attn + (size_t)i * 256 * 96, b_attn + i * 96, lgt, 96, 256, 0);
    // val = x @ W_val + b_val                [M,256]
    gemm_kernel<<<dim3(4, MT), 256, 0, stream>>>(
        x, nullptr, W_val + (size_t)i * 256 * 256, b_val + i * 256, val, 256, 256, 0);
    // deformable attention sampling          [M,256]
    deform_kernel<<<MROWS, 256, 0, stream>>>(val, lgt, offb, attn);
    // proj = attn @ W_out + b_out            [M,256]  (proj aliases val; val is dead)
    gemm_kernel<<<dim3(4, MT), 256, 0, stream>>>(
        attn, nullptr, W_out + (size_t)i * 256 * 256, b_out + i * 256, proj, 256, 256, 0);
    // x = LN(x + proj)
    add_ln_kernel<<<MROWS / 4, 256, 0, stream>>>(x, proj, ln1g + i * 256, ln1b + i * 256);
    // ffh = relu(x @ W_ff1 + b_ff1)          [M,1024]
    gemm_kernel<<<dim3(16, MT), 256, 0, stream>>>(
        x, nullptr, W_ff1 + (size_t)i * 256 * 1024, b_ff1 + i * 1024, ffh, 1024, 256, 1);
    // ffres = ffh @ W_ff2 + b_ff2            [M,256]  (aliases off/logits; dead)
    gemm_kernel<<<dim3(4, MT), 256, 0, stream>>>(
        ffh, nullptr, W_ff2 + (size_t)i * 1024 * 256, b_ff2 + i * 256, ffres, 256, 1024, 0);
    // x = LN(x + ffres)
    add_ln_kernel<<<MROWS / 4, 256, 0, stream>>>(x, ffres, ln2g + i * 256, ln2b + i * 256);
  }

  hipMemcpyAsync(d_out, x, Msz * 256 * sizeof(float), hipMemcpyDeviceToDevice, stream);
}

// Round 2
// 1517.157 us; speedup vs baseline: 2.8932x; 2.8932x over previous
//
#include <hip/hip_runtime.h>

// MSDeformAttn pixel decoder. v1: bf16-MFMA GEMMs (m97-style 128x128 tile),
// float2 deform kernel. fp32 residual stream + LN.
// D=256, NH=8, DH=32, NL=3, NP=4, DFF=1024, B=4, Q=5376, M=B*Q=21504.

#define DMODEL 256
#define NLAYERS 6
#define BATCH 4
#define QTOT 5376
#define MROWS (BATCH * QTOT)   // 21504 = 168*128

typedef __bf16 bf16x8 __attribute__((ext_vector_type(8)));
typedef __bf16 bf16x4 __attribute__((ext_vector_type(4)));
typedef __bf16 bf16x2 __attribute__((ext_vector_type(2)));
typedef float floatx4 __attribute__((ext_vector_type(4)));

// ---------------------------------------------------------------------------
// Flatten: src [B,D,H,W] -> x fp32 + xb bf16 [B,Q,D]; pos + level_embed -> pos
// ---------------------------------------------------------------------------
__global__ __launch_bounds__(256) void flatten_kernel(
    const float* __restrict__ s0, const float* __restrict__ p0,
    const float* __restrict__ s1, const float* __restrict__ p1,
    const float* __restrict__ s2, const float* __restrict__ p2,
    const float* __restrict__ lvl, float* __restrict__ x,
    float* __restrict__ pos, __bf16* __restrict__ xb) {
  int bq = blockIdx.x;               // 0..M-1
  int b = bq / QTOT, q = bq % QTOT;
  int d = threadIdx.x;               // 0..255
  const float* sp; const float* pp; int l, p, hw;
  if (q < 4096)      { l = 0; p = q;        hw = 4096; sp = s0; pp = p0; }
  else if (q < 5120) { l = 1; p = q - 4096; hw = 1024; sp = s1; pp = p1; }
  else               { l = 2; p = q - 5120; hw = 256;  sp = s2; pp = p2; }
  size_t si = ((size_t)(b * DMODEL + d)) * hw + p;
  float v = sp[si];
  x[(size_t)bq * DMODEL + d] = v;
  xb[(size_t)bq * DMODEL + d] = (__bf16)v;
  pos[(size_t)bq * DMODEL + d] = pp[si] + lvl[l * DMODEL + d];
}

// ---------------------------------------------------------------------------
// qb = bf16(x + pos), 4 elems/thread
// ---------------------------------------------------------------------------
__global__ __launch_bounds__(256) void qb_kernel(
    const float* __restrict__ x, const float* __restrict__ pos,
    __bf16* __restrict__ qb) {
  int i = blockIdx.x * 256 + threadIdx.x;   // i < M*64
  float4 xv = ((const float4*)x)[i];
  float4 pv = ((const float4*)pos)[i];
  bf16x4 o;
  o[0] = (__bf16)(xv.x + pv.x);
  o[1] = (__bf16)(xv.y + pv.y);
  o[2] = (__bf16)(xv.z + pv.z);
  o[3] = (__bf16)(xv.w + pv.w);
  *(bf16x4*)&qb[(size_t)i * 4] = o;
}

// ---------------------------------------------------------------------------
// Weight pack: W [L][K][N] fp32 -> Wt [L][N][K] bf16 (transposed)
// ---------------------------------------------------------------------------
__global__ __launch_bounds__(256) void pack_wt_kernel(
    const float* __restrict__ W, __bf16* __restrict__ Wt, int K, int N) {
  int l = blockIdx.y;
  int idx = blockIdx.x * 256 + threadIdx.x;  // n*K + k
  int n = idx / K, k = idx - n * K;
  Wt[(size_t)l * N * K + idx] = (__bf16)W[(size_t)l * K * N + (size_t)k * N + n];
}

// Combined W_off|W_attn pack: -> Wt [L][384][256] bf16 (cols 288..383 zero)
__global__ __launch_bounds__(256) void pack_qp_kernel(
    const float* __restrict__ Woff, const float* __restrict__ Wattn,
    const float* __restrict__ boff, const float* __restrict__ battn,
    __bf16* __restrict__ Wt, float* __restrict__ bqp) {
  int l = blockIdx.y;
  int idx = blockIdx.x * 256 + threadIdx.x;  // n*256 + k
  int n = idx >> 8, k = idx & 255;
  float v = 0.f;
  if (n < 192)      v = Woff[((size_t)l * 256 + k) * 192 + n];
  else if (n < 288) v = Wattn[((size_t)l * 256 + k) * 96 + (n - 192)];
  Wt[(size_t)l * 384 * 256 + idx] = (__bf16)v;
  if (k == 0) {
    float b = 0.f;
    if (n < 192)      b = boff[l * 192 + n];
    else if (n < 288) b = battn[l * 96 + (n - 192)];
    bqp[l * 384 + n] = b;
  }
}

// ---------------------------------------------------------------------------
// bf16 MFMA GEMM: C[M,N] = A[M,K]bf16 @ Wt[N,K]bf16^T + bias.
// 128x128 tile, BK=32, 4 waves (2x2), 16x16x32 MFMA, global_load_lds w16.
// ---------------------------------------------------------------------------
template<int RELU, int BF16OUT>
__global__ __launch_bounds__(256) void gemm_bf16_kernel(
    const __bf16* __restrict__ A, const __bf16* __restrict__ Wt,
    const float* __restrict__ bias, float* __restrict__ C,
    __bf16* __restrict__ Cb, int N, int K) {
  __shared__ __bf16 As[128 * 32];
  __shared__ __bf16 Bs[128 * 32];
  int t = threadIdx.x;
  int lane = t & 63, wid = t >> 6;
  int wr = wid >> 1, wc = wid & 1;
  int row0 = blockIdx.y * 128;
  int n0 = blockIdx.x * 128;

  floatx4 acc[4][4] = {};

  int srow = lane >> 2;              // 0..15 within 16-row chunk
  int skoff = (lane & 3) * 8;        // k element offset (16B granules)
  const __bf16* Abase = A + (size_t)(row0 + srow) * K + skoff;
  const __bf16* Bbase = Wt + (size_t)(n0 + srow) * K + skoff;

  for (int k0 = 0; k0 < K; k0 += 32) {
    __syncthreads();
#pragma unroll
    for (int cc = 0; cc < 2; ++cc) {
      int c = wid * 2 + cc;          // chunk 0..7, wave-uniform
      __builtin_amdgcn_global_load_lds(
          (__attribute__((address_space(1))) void*)(Abase + (size_t)c * 16 * K + k0),
          (__attribute__((address_space(3))) void*)(As + c * 512), 16, 0, 0);
      __builtin_amdgcn_global_load_lds(
          (__attribute__((address_space(1))) void*)(Bbase + (size_t)c * 16 * K + k0),
          (__attribute__((address_space(3))) void*)(Bs + c * 512), 16, 0, 0);
    }
    __syncthreads();
    bf16x8 af[4], bfr[4];
#pragma unroll
    for (int i = 0; i < 4; ++i)
      af[i] = *(const bf16x8*)&As[(wr * 64 + i * 16 + (lane & 15)) * 32 + (lane >> 4) * 8];
#pragma unroll
    for (int j = 0; j < 4; ++j)
      bfr[j] = *(const bf16x8*)&Bs[(wc * 64 + j * 16 + (lane & 15)) * 32 + (lane >> 4) * 8];
#pragma unroll
    for (int i = 0; i < 4; ++i)
#pragma unroll
      for (int j = 0; j < 4; ++j)
        acc[i][j] = __builtin_amdgcn_mfma_f32_16x16x32_bf16(af[i], bfr[j], acc[i][j], 0, 0, 0);
  }

  int orow = row0 + wr * 64 + (lane >> 4) * 4;
  int ocol = n0 + wc * 64 + (lane & 15);
#pragma unroll
  for (int i = 0; i < 4; ++i) {
#pragma unroll
    for (int j = 0; j < 4; ++j) {
      int col = ocol + j * 16;
      float bv = bias[col];
#pragma unroll
      for (int r = 0; r < 4; ++r) {
        int row = orow + i * 16 + r;
        float v = acc[i][j][r] + bv;
        if (RELU) v = fmaxf(v, 0.f);
        if (BF16OUT) Cb[(size_t)row * N + col] = (__bf16)v;
        else         C[(size_t)row * N + col] = v;
      }
    }
  }
}

// ---------------------------------------------------------------------------
// Deformable sampling + per-head softmax. Block = 2 queries x 128 threads.
// thread: hid = tq>>4, channel pair = (tq&15)*2. Output bf16.
// ---------------------------------------------------------------------------
__global__ __launch_bounds__(256) void deform_kernel(
    const float* __restrict__ val, const float* __restrict__ qproj,
    __bf16* __restrict__ out) {
  int bq = blockIdx.x * 2 + (threadIdx.x >> 7);
  int b = bq / QTOT, q = bq % QTOT;
  int tq = threadIdx.x & 127;
  int hid = tq >> 4, dp = tq & 15;

  int p, wsrc;
  if (q < 4096)      { p = q;        wsrc = 64; }
  else if (q < 5120) { p = q - 4096; wsrc = 32; }
  else               { p = q - 5120; wsrc = 16; }
  float inv = 1.0f / (float)wsrc;
  float refx = ((float)(p % wsrc) + 0.5f) * inv;
  float refy = ((float)(p / wsrc) + 0.5f) * inv;

  const float* lg = qproj + (size_t)bq * 384 + 192 + hid * 12;
  float aw[12];
  float mx = -1e30f;
#pragma unroll
  for (int k = 0; k < 12; ++k) { aw[k] = lg[k]; mx = fmaxf(mx, aw[k]); }
  float s = 0.f;
#pragma unroll
  for (int k = 0; k < 12; ++k) { aw[k] = __expf(aw[k] - mx); s += aw[k]; }
  float invs = 1.0f / s;

  const float* ob = qproj + (size_t)bq * 384 + hid * 24;
  const float* vb = val + (size_t)b * QTOT * DMODEL + hid * 32 + dp * 2;

  const int starts[3] = {0, 4096, 5120};
  const int wls[3] = {64, 32, 16};
  float ax = 0.f, ay = 0.f;
#pragma unroll
  for (int l = 0; l < 3; ++l) {
    int wl = wls[l], start = starts[l];
    float fwl = (float)wl;
#pragma unroll
    for (int pp = 0; pp < 4; ++pp) {
      float wcomb = aw[l * 4 + pp] * invs;
      float fx = refx * fwl + ob[(l * 4 + pp) * 2 + 0] - 0.5f;
      float fy = refy * fwl + ob[(l * 4 + pp) * 2 + 1] - 0.5f;
      float x0f = floorf(fx), y0f = floorf(fy);
      float lx = fx - x0f, ly = fy - y0f;
      int x0 = (int)x0f, y0 = (int)y0f;
#pragma unroll
      for (int c = 0; c < 4; ++c) {
        int dx = c & 1, dy = c >> 1;
        int xi = x0 + dx, yi = y0 + dy;
        if (xi >= 0 && xi < wl && yi >= 0 && yi < wl) {
          float wgt = (dx ? lx : 1.f - lx) * (dy ? ly : 1.f - ly) * wcomb;
          const float* vp = vb + (size_t)(start + yi * wl + xi) * DMODEL;
          float2 v = *(const float2*)vp;
          ax = fmaf(wgt, v.x, ax);
          ay = fmaf(wgt, v.y, ay);
        }
      }
    }
  }
  bf16x2 o;
  o[0] = (__bf16)ax;
  o[1] = (__bf16)ay;
  *(bf16x2*)&out[(size_t)bq * DMODEL + hid * 32 + dp * 2] = o;
}

// ---------------------------------------------------------------------------
// x = LayerNorm(x + res); also write xb = bf16(x). One wave per row.
// ---------------------------------------------------------------------------
__global__ __launch_bounds__(256) void add_ln_kernel(
    float* __restrict__ x, const float* __restrict__ res,
    const float* __restrict__ g, const float* __restrict__ bta,
    __bf16* __restrict__ xb) {
  int row = blockIdx.x * 4 + (threadIdx.x >> 6);
  int lane = threadIdx.x & 63;
  float4 xv = ((const float4*)(x + (size_t)row * DMODEL))[lane];
  float4 rv = ((const float4*)(res + (size_t)row * DMODEL))[lane];
  xv.x += rv.x; xv.y += rv.y; xv.z += rv.z; xv.w += rv.w;
  float s = xv.x + xv.y + xv.z + xv.w;
  float sq = xv.x * xv.x + xv.y * xv.y + xv.z * xv.z + xv.w * xv.w;
#pragma unroll
  for (int o = 32; o >= 1; o >>= 1) {
    s += __shfl_xor(s, o);
    sq += __shfl_xor(sq, o);
  }
  float mean = s * (1.f / 256.f);
  float var = sq * (1.f / 256.f) - mean * mean;
  float rstd = rsqrtf(var + 1e-5f);
  int c = lane * 4;
  float4 gv = *(const float4*)(g + c);
  float4 bv = *(const float4*)(bta + c);
  float4 o4;
  o4.x = (xv.x - mean) * rstd * gv.x + bv.x;
  o4.y = (xv.y - mean) * rstd * gv.y + bv.y;
  o4.z = (xv.z - mean) * rstd * gv.z + bv.z;
  o4.w = (xv.w - mean) * rstd * gv.w + bv.w;
  ((float4*)(x + (size_t)row * DMODEL))[lane] = o4;
  bf16x4 ob;
  ob[0] = (__bf16)o4.x; ob[1] = (__bf16)o4.y;
  ob[2] = (__bf16)o4.z; ob[3] = (__bf16)o4.w;
  *(bf16x4*)&xb[(size_t)row * DMODEL + c] = ob;
}

// ---------------------------------------------------------------------------
extern "C" void kernel_launch(void* const* d_in, const int* in_sizes, int n_in,
                              void* d_out, int out_size, void* d_ws, size_t ws_size,
                              hipStream_t stream) {
  const float* src0 = (const float*)d_in[0];
  const float* pos0 = (const float*)d_in[1];
  const float* src1 = (const float*)d_in[2];
  const float* pos1 = (const float*)d_in[3];
  const float* src2 = (const float*)d_in[4];
  const float* pos2 = (const float*)d_in[5];
  const float* lvl  = (const float*)d_in[6];
  const float* W_off  = (const float*)d_in[7];
  const float* b_off  = (const float*)d_in[8];
  const float* W_attn = (const float*)d_in[9];
  const float* b_attn = (const float*)d_in[10];
  const float* W_val  = (const float*)d_in[11];
  const float* b_val  = (const float*)d_in[12];
  const float* W_out  = (const float*)d_in[13];
  const float* b_out  = (const float*)d_in[14];
  const float* ln1g = (const float*)d_in[15];
  const float* ln1b = (const float*)d_in[16];
  const float* W_ff1 = (const float*)d_in[17];
  const float* b_ff1 = (const float*)d_in[18];
  const float* W_ff2 = (const float*)d_in[19];
  const float* b_ff2 = (const float*)d_in[20];
  const float* ln2g = (const float*)d_in[21];
  const float* ln2b = (const float*)d_in[22];

  const size_t M = (size_t)MROWS;
  char* w = (char*)d_ws;
  float*  x     = (float*)w;                 w += M * 256 * 4;
  float*  pos   = (float*)w;                 w += M * 256 * 4;
  __bf16* xb    = (__bf16*)w;                w += M * 256 * 2;
  __bf16* qb    = (__bf16*)w;                w += M * 256 * 2;   // aliased: attn_bf
  float*  qproj = (float*)w;                 w += M * 384 * 4;   // aliased: ffres
  float*  val   = (float*)w;                 w += M * 256 * 4;   // aliased: proj
  __bf16* ffh   = (__bf16*)w;                w += M * 1024 * 2;
  __bf16* wqp_t = (__bf16*)w;                w += (size_t)NLAYERS * 384 * 256 * 2;
  __bf16* wval_t= (__bf16*)w;                w += (size_t)NLAYERS * 256 * 256 * 2;
  __bf16* wout_t= (__bf16*)w;                w += (size_t)NLAYERS * 256 * 256 * 2;
  __bf16* wff1_t= (__bf16*)w;                w += (size_t)NLAYERS * 1024 * 256 * 2;
  __bf16* wff2_t= (__bf16*)w;                w += (size_t)NLAYERS * 256 * 1024 * 2;
  float*  bqp   = (float*)w;                 w += (size_t)NLAYERS * 384 * 4;
  __bf16* attn_bf = qb;
  float*  proj  = val;
  float*  ffres = qproj;

  // weight packs (once per call)
  pack_qp_kernel<<<dim3(384, NLAYERS), 256, 0, stream>>>(W_off, W_attn, b_off, b_attn, wqp_t, bqp);
  pack_wt_kernel<<<dim3(256, NLAYERS), 256, 0, stream>>>(W_val, wval_t, 256, 256);
  pack_wt_kernel<<<dim3(256, NLAYERS), 256, 0, stream>>>(W_out, wout_t, 256, 256);
  pack_wt_kernel<<<dim3(1024, NLAYERS), 256, 0, stream>>>(W_ff1, wff1_t, 256, 1024);
  pack_wt_kernel<<<dim3(1024, NLAYERS), 256, 0, stream>>>(W_ff2, wff2_t, 1024, 256);

  flatten_kernel<<<MROWS, 256, 0, stream>>>(src0, pos0, src1, pos1, src2, pos2,
                                            lvl, x, pos, xb);

  const int MT = MROWS / 128;  // 168
  for (int i = 0; i < NLAYERS; ++i) {
    qb_kernel<<<MROWS / 4, 256, 0, stream>>>(x, pos, qb);
    gemm_bf16_kernel<0, 0><<<dim3(3, MT), 256, 0, stream>>>(
        qb, wqp_t + (size_t)i * 384 * 256, bqp + i * 384, qproj, nullptr, 384, 256);
    gemm_bf16_kernel<0, 0><<<dim3(2, MT), 256, 0, stream>>>(
        xb, wval_t + (size_t)i * 256 * 256, b_val + i * 256, val, nullptr, 256, 256);
    deform_kernel<<<MROWS / 2, 256, 0, stream>>>(val, qproj, attn_bf);
    gemm_bf16_kernel<0, 0><<<dim3(2, MT), 256, 0, stream>>>(
        attn_bf, wout_t + (size_t)i * 256 * 256, b_out + i * 256, proj, nullptr, 256, 256);
    add_ln_kernel<<<MROWS / 4, 256, 0, stream>>>(x, proj, ln1g + i * 256, ln1b + i * 256, xb);
    gemm_bf16_kernel<1, 1><<<dim3(8, MT), 256, 0, stream>>>(
        xb, wff1_t + (size_t)i * 1024 * 256, b_ff1 + i * 1024, nullptr, ffh, 1024, 256);
    gemm_bf16_kernel<0, 0><<<dim3(2, MT), 256, 0, stream>>>(
        ffh, wff2_t + (size_t)i * 256 * 1024, b_ff2 + i * 256, ffres, nullptr, 256, 1024);
    add_ln_kernel<<<MROWS / 4, 256, 0, stream>>>(x, ffres, ln2g + i * 256, ln2b + i * 256, xb);
  }

  hipMemcpyAsync(d_out, x, M * 256 * 4, hipMemcpyDeviceToDevice, stream);
}

// Round 3
// 1163.292 us; speedup vs baseline: 3.7733x; 1.3042x over previous
//
#include <hip/hip_runtime.h>

// MSDeformAttn pixel decoder. v2: bf16-MFMA GEMMs (fused qproj|val N=640),
// float4 deform kernel (4ch/thread), last LN writes d_out directly.
// D=256, NH=8, DH=32, NL=3, NP=4, DFF=1024, B=4, Q=5376, M=B*Q=21504.

#define DMODEL 256
#define NLAYERS 6
#define BATCH 4
#define QTOT 5376
#define MROWS (BATCH * QTOT)   // 21504 = 168*128

typedef __bf16 bf16x8 __attribute__((ext_vector_type(8)));
typedef __bf16 bf16x4 __attribute__((ext_vector_type(4)));
typedef float floatx4 __attribute__((ext_vector_type(4)));

// ---------------------------------------------------------------------------
// Flatten: src [B,D,H,W] -> x fp32 + xb bf16 [B,Q,D]; pos + level_embed -> pos
// ---------------------------------------------------------------------------
__global__ __launch_bounds__(256) void flatten_kernel(
    const float* __restrict__ s0, const float* __restrict__ p0,
    const float* __restrict__ s1, const float* __restrict__ p1,
    const float* __restrict__ s2, const float* __restrict__ p2,
    const float* __restrict__ lvl, float* __restrict__ x,
    float* __restrict__ pos, __bf16* __restrict__ xb) {
  int bq = blockIdx.x;
  int b = bq / QTOT, q = bq % QTOT;
  int d = threadIdx.x;
  const float* sp; const float* pp; int l, p, hw;
  if (q < 4096)      { l = 0; p = q;        hw = 4096; sp = s0; pp = p0; }
  else if (q < 5120) { l = 1; p = q - 4096; hw = 1024; sp = s1; pp = p1; }
  else               { l = 2; p = q - 5120; hw = 256;  sp = s2; pp = p2; }
  size_t si = ((size_t)(b * DMODEL + d)) * hw + p;
  float v = sp[si];
  x[(size_t)bq * DMODEL + d] = v;
  xb[(size_t)bq * DMODEL + d] = (__bf16)v;
  pos[(size_t)bq * DMODEL + d] = pp[si] + lvl[l * DMODEL + d];
}

// ---------------------------------------------------------------------------
// qb = bf16(x + pos), 4 elems/thread
// ---------------------------------------------------------------------------
__global__ __launch_bounds__(256) void qb_kernel(
    const float* __restrict__ x, const float* __restrict__ pos,
    __bf16* __restrict__ qb) {
  int i = blockIdx.x * 256 + threadIdx.x;
  float4 xv = ((const float4*)x)[i];
  float4 pv = ((const float4*)pos)[i];
  bf16x4 o;
  o[0] = (__bf16)(xv.x + pv.x);
  o[1] = (__bf16)(xv.y + pv.y);
  o[2] = (__bf16)(xv.z + pv.z);
  o[3] = (__bf16)(xv.w + pv.w);
  *(bf16x4*)&qb[(size_t)i * 4] = o;
}

// ---------------------------------------------------------------------------
// Weight pack: W [L][K][N] fp32 -> Wt [L][N][K] bf16 (transposed)
// ---------------------------------------------------------------------------
__global__ __launch_bounds__(256) void pack_wt_kernel(
    const float* __restrict__ W, __bf16* __restrict__ Wt, int K, int N) {
  int l = blockIdx.y;
  int idx = blockIdx.x * 256 + threadIdx.x;
  int n = idx / K, k = idx - n * K;
  Wt[(size_t)l * N * K + idx] = (__bf16)W[(size_t)l * K * N + (size_t)k * N + n];
}

// Combined [W_off|W_attn|pad|W_val] pack -> Wt [L][640][256] bf16 + bias [L][640]
__global__ __launch_bounds__(256) void pack_qv_kernel(
    const float* __restrict__ Woff, const float* __restrict__ Wattn,
    const float* __restrict__ Wval,
    const float* __restrict__ boff, const float* __restrict__ battn,
    const float* __restrict__ bval,
    __bf16* __restrict__ Wt, float* __restrict__ bc) {
  int l = blockIdx.y;
  int n = blockIdx.x;          // 0..639
  int k = threadIdx.x;         // 0..255
  float v = 0.f;
  if (n < 192)      v = Woff[((size_t)l * 256 + k) * 192 + n];
  else if (n < 288) v = Wattn[((size_t)l * 256 + k) * 96 + (n - 192)];
  else if (n >= 384) v = Wval[((size_t)l * 256 + k) * 256 + (n - 384)];
  Wt[((size_t)l * 640 + n) * 256 + k] = (__bf16)v;
  if (k == 0) {
    float b = 0.f;
    if (n < 192)      b = boff[l * 192 + n];
    else if (n < 288) b = battn[l * 96 + (n - 192)];
    else if (n >= 384) b = bval[l * 256 + (n - 384)];
    bc[l * 640 + n] = b;
  }
}

// ---------------------------------------------------------------------------
// Shared MFMA tile core: acc[4][4] over 128x128 tile, BK=32, 4 waves (2x2).
// ---------------------------------------------------------------------------
#define GEMM_CORE(A_, B_, K_)                                                  \
  for (int k0 = 0; k0 < (K_); k0 += 32) {                                      \
    __syncthreads();                                                           \
    _Pragma("unroll")                                                          \
    for (int cc = 0; cc < 2; ++cc) {                                           \
      int c = wid * 2 + cc;                                                    \
      __builtin_amdgcn_global_load_lds(                                        \
          (__attribute__((address_space(1))) void*)((A_) + (size_t)c * 16 * (K_) + k0), \
          (__attribute__((address_space(3))) void*)(As + c * 512), 16, 0, 0);  \
      __builtin_amdgcn_global_load_lds(                                        \
          (__attribute__((address_space(1))) void*)((B_) + (size_t)c * 16 * (K_) + k0), \
          (__attribute__((address_space(3))) void*)(Bs + c * 512), 16, 0, 0);  \
    }                                                                          \
    __syncthreads();                                                           \
    bf16x8 af[4], bfr[4];                                                      \
    _Pragma("unroll")                                                          \
    for (int i = 0; i < 4; ++i)                                                \
      af[i] = *(const bf16x8*)&As[(wr * 64 + i * 16 + (lane & 15)) * 32 + (lane >> 4) * 8]; \
    _Pragma("unroll")                                                          \
    for (int j = 0; j < 4; ++j)                                                \
      bfr[j] = *(const bf16x8*)&Bs[(wc * 64 + j * 16 + (lane & 15)) * 32 + (lane >> 4) * 8]; \
    _Pragma("unroll")                                                          \
    for (int i = 0; i < 4; ++i)                                                \
      _Pragma("unroll")                                                        \
      for (int j = 0; j < 4; ++j)                                              \
        acc[i][j] = __builtin_amdgcn_mfma_f32_16x16x32_bf16(af[i], bfr[j], acc[i][j], 0, 0, 0); \
  }

// ---------------------------------------------------------------------------
// Generic bf16 GEMM: C = A[M,K] @ Wt[N,K]^T + bias
// ---------------------------------------------------------------------------
template<int RELU, int BF16OUT>
__global__ __launch_bounds__(256) void gemm_bf16_kernel(
    const __bf16* __restrict__ A, const __bf16* __restrict__ Wt,
    const float* __restrict__ bias, float* __restrict__ C,
    __bf16* __restrict__ Cb, int N, int K) {
  __shared__ __bf16 As[128 * 32];
  __shared__ __bf16 Bs[128 * 32];
  int t = threadIdx.x;
  int lane = t & 63, wid = t >> 6;
  int wr = wid >> 1, wc = wid & 1;
  int row0 = blockIdx.y * 128;
  int n0 = blockIdx.x * 128;
  floatx4 acc[4][4] = {};
  int srow = lane >> 2;
  int skoff = (lane & 3) * 8;
  const __bf16* Abase = A + (size_t)(row0 + srow) * K + skoff;
  const __bf16* Bbase = Wt + (size_t)(n0 + srow) * K + skoff;
  GEMM_CORE(Abase, Bbase, K)
  int orow = row0 + wr * 64 + (lane >> 4) * 4;
  int ocol = n0 + wc * 64 + (lane & 15);
#pragma unroll
  for (int i = 0; i < 4; ++i)
#pragma unroll
    for (int j = 0; j < 4; ++j) {
      int col = ocol + j * 16;
      float bv = bias[col];
#pragma unroll
      for (int r = 0; r < 4; ++r) {
        int row = orow + i * 16 + r;
        float v = acc[i][j][r] + bv;
        if (RELU) v = fmaxf(v, 0.f);
        if (BF16OUT) Cb[(size_t)row * N + col] = (__bf16)v;
        else         C[(size_t)row * N + col] = v;
      }
    }
}

// ---------------------------------------------------------------------------
// Fused [qproj|val] GEMM: bn<3 -> qproj = qb@Wqp (cols bn*128, stride 384)
//                          bn>=3 -> val  = xb@Wv  (cols (bn-3)*128, stride 256)
// Wt is packed [640][256].
// ---------------------------------------------------------------------------
__global__ __launch_bounds__(256) void gemm_qv_kernel(
    const __bf16* __restrict__ qb, const __bf16* __restrict__ xb,
    const __bf16* __restrict__ Wt, const float* __restrict__ bias,
    float* __restrict__ qproj, float* __restrict__ val) {
  __shared__ __bf16 As[128 * 32];
  __shared__ __bf16 Bs[128 * 32];
  int t = threadIdx.x;
  int lane = t & 63, wid = t >> 6;
  int wr = wid >> 1, wc = wid & 1;
  int bn = blockIdx.x;                    // 0..4
  int row0 = blockIdx.y * 128;
  int n0 = bn * 128;                      // row in packed Wt
  const __bf16* A = (bn < 3) ? qb : xb;
  floatx4 acc[4][4] = {};
  int srow = lane >> 2;
  int skoff = (lane & 3) * 8;
  const __bf16* Abase = A + (size_t)(row0 + srow) * 256 + skoff;
  const __bf16* Bbase = Wt + (size_t)(n0 + srow) * 256 + skoff;
  GEMM_CORE(Abase, Bbase, 256)
  float* C; int cstride, cbase;
  if (bn < 3) { C = qproj; cstride = 384; cbase = n0; }
  else        { C = val;   cstride = 256; cbase = n0 - 384; }
  int orow = row0 + wr * 64 + (lane >> 4) * 4;
  int ocol = wc * 64 + (lane & 15);
#pragma unroll
  for (int i = 0; i < 4; ++i)
#pragma unroll
    for (int j = 0; j < 4; ++j) {
      int col = ocol + j * 16;
      float bv = bias[n0 + col];
#pragma unroll
      for (int r = 0; r < 4; ++r) {
        int row = orow + i * 16 + r;
        C[(size_t)row * cstride + cbase + col] = acc[i][j][r] + bv;
      }
    }
}

// ---------------------------------------------------------------------------
// Deformable sampling + per-head softmax. 64 threads/query: hid = tq>>3,
// channel quad = (tq&7)*4. float4 gathers. Output bf16.
// ---------------------------------------------------------------------------
__global__ __launch_bounds__(256) void deform_kernel(
    const float* __restrict__ val, const float* __restrict__ qproj,
    __bf16* __restrict__ out) {
  int bq = blockIdx.x * 4 + (threadIdx.x >> 6);
  int b = bq / QTOT, q = bq % QTOT;
  int tq = threadIdx.x & 63;
  int hid = tq >> 3, dq = (tq & 7) * 4;

  int p, wsrc;
  if (q < 4096)      { p = q;        wsrc = 64; }
  else if (q < 5120) { p = q - 4096; wsrc = 32; }
  else               { p = q - 5120; wsrc = 16; }
  float inv = 1.0f / (float)wsrc;
  float refx = ((float)(p % wsrc) + 0.5f) * inv;
  float refy = ((float)(p / wsrc) + 0.5f) * inv;

  const float* base = qproj + (size_t)bq * 384;
  float aw[12], ob[24];
  *(float4*)&aw[0] = *(const float4*)(base + 192 + hid * 12);
  *(float4*)&aw[4] = *(const float4*)(base + 192 + hid * 12 + 4);
  *(float4*)&aw[8] = *(const float4*)(base + 192 + hid * 12 + 8);
#pragma unroll
  for (int i = 0; i < 6; ++i)
    *(float4*)&ob[i * 4] = *(const float4*)(base + hid * 24 + i * 4);

  float mx = -1e30f;
#pragma unroll
  for (int k = 0; k < 12; ++k) mx = fmaxf(mx, aw[k]);
  float s = 0.f;
#pragma unroll
  for (int k = 0; k < 12; ++k) { aw[k] = __expf(aw[k] - mx); s += aw[k]; }
  float invs = 1.0f / s;

  const float* vb = val + ((size_t)b * QTOT) * DMODEL + hid * 32 + dq;

  const int starts[3] = {0, 4096, 5120};
  const int wls[3] = {64, 32, 16};
  float4 acc = make_float4(0.f, 0.f, 0.f, 0.f);
#pragma unroll
  for (int l = 0; l < 3; ++l) {
    int wl = wls[l], start = starts[l];
    float fwl = (float)wl;
#pragma unroll
    for (int pp = 0; pp < 4; ++pp) {
      float wcomb = aw[l * 4 + pp] * invs;
      float fx = refx * fwl + ob[(l * 4 + pp) * 2 + 0] - 0.5f;
      float fy = refy * fwl + ob[(l * 4 + pp) * 2 + 1] - 0.5f;
      float x0f = floorf(fx), y0f = floorf(fy);
      float lx = fx - x0f, ly = fy - y0f;
      int x0 = (int)x0f, y0 = (int)y0f;
#pragma unroll
      for (int c = 0; c < 4; ++c) {
        int dx = c & 1, dy = c >> 1;
        int xi = x0 + dx, yi = y0 + dy;
        if (xi >= 0 && xi < wl && yi >= 0 && yi < wl) {
          float wgt = (dx ? lx : 1.f - lx) * (dy ? ly : 1.f - ly) * wcomb;
          float4 v = *(const float4*)(vb + (size_t)(start + yi * wl + xi) * DMODEL);
          acc.x = fmaf(wgt, v.x, acc.x);
          acc.y = fmaf(wgt, v.y, acc.y);
          acc.z = fmaf(wgt, v.z, acc.z);
          acc.w = fmaf(wgt, v.w, acc.w);
        }
      }
    }
  }
  bf16x4 o;
  o[0] = (__bf16)acc.x; o[1] = (__bf16)acc.y;
  o[2] = (__bf16)acc.z; o[3] = (__bf16)acc.w;
  *(bf16x4*)&out[(size_t)bq * DMODEL + hid * 32 + dq] = o;
}

// ---------------------------------------------------------------------------
// xout = LayerNorm(x + res); xb = bf16(xout). One wave per row.
// ---------------------------------------------------------------------------
__global__ __launch_bounds__(256) void add_ln_kernel(
    const float* __restrict__ x, const float* __restrict__ res,
    const float* __restrict__ g, const float* __restrict__ bta,
    float* __restrict__ xout, __bf16* __restrict__ xb) {
  int row = blockIdx.x * 4 + (threadIdx.x >> 6);
  int lane = threadIdx.x & 63;
  float4 xv = ((const float4*)(x + (size_t)row * DMODEL))[lane];
  float4 rv = ((const float4*)(res + (size_t)row * DMODEL))[lane];
  xv.x += rv.x; xv.y += rv.y; xv.z += rv.z; xv.w += rv.w;
  float s = xv.x + xv.y + xv.z + xv.w;
  float sq = xv.x * xv.x + xv.y * xv.y + xv.z * xv.z + xv.w * xv.w;
#pragma unroll
  for (int o = 32; o >= 1; o >>= 1) {
    s += __shfl_xor(s, o);
    sq += __shfl_xor(sq, o);
  }
  float mean = s * (1.f / 256.f);
  float var = sq * (1.f / 256.f) - mean * mean;
  float rstd = rsqrtf(var + 1e-5f);
  int c = lane * 4;
  float4 gv = *(const float4*)(g + c);
  float4 bv = *(const float4*)(bta + c);
  float4 o4;
  o4.x = (xv.x - mean) * rstd * gv.x + bv.x;
  o4.y = (xv.y - mean) * rstd * gv.y + bv.y;
  o4.z = (xv.z - mean) * rstd * gv.z + bv.z;
  o4.w = (xv.w - mean) * rstd * gv.w + bv.w;
  ((float4*)(xout + (size_t)row * DMODEL))[lane] = o4;
  bf16x4 ob;
  ob[0] = (__bf16)o4.x; ob[1] = (__bf16)o4.y;
  ob[2] = (__bf16)o4.z; ob[3] = (__bf16)o4.w;
  *(bf16x4*)&xb[(size_t)row * DMODEL + c] = ob;
}

// ---------------------------------------------------------------------------
extern "C" void kernel_launch(void* const* d_in, const int* in_sizes, int n_in,
                              void* d_out, int out_size, void* d_ws, size_t ws_size,
                              hipStream_t stream) {
  const float* src0 = (const float*)d_in[0];
  const float* pos0 = (const float*)d_in[1];
  const float* src1 = (const float*)d_in[2];
  const float* pos1 = (const float*)d_in[3];
  const float* src2 = (const float*)d_in[4];
  const float* pos2 = (const float*)d_in[5];
  const float* lvl  = (const float*)d_in[6];
  const float* W_off  = (const float*)d_in[7];
  const float* b_off  = (const float*)d_in[8];
  const float* W_attn = (const float*)d_in[9];
  const float* b_attn = (const float*)d_in[10];
  const float* W_val  = (const float*)d_in[11];
  const float* b_val  = (const float*)d_in[12];
  const float* W_out  = (const float*)d_in[13];
  const float* b_out  = (const float*)d_in[14];
  const float* ln1g = (const float*)d_in[15];
  const float* ln1b = (const float*)d_in[16];
  const float* W_ff1 = (const float*)d_in[17];
  const float* b_ff1 = (const float*)d_in[18];
  const float* W_ff2 = (const float*)d_in[19];
  const float* b_ff2 = (const float*)d_in[20];
  const float* ln2g = (const float*)d_in[21];
  const float* ln2b = (const float*)d_in[22];

  const size_t M = (size_t)MROWS;
  char* w = (char*)d_ws;
  float*  x     = (float*)w;                 w += M * 256 * 4;
  float*  pos   = (float*)w;                 w += M * 256 * 4;
  __bf16* xb    = (__bf16*)w;                w += M * 256 * 2;
  __bf16* qb    = (__bf16*)w;                w += M * 256 * 2;   // alias: attn_bf
  float*  qproj = (float*)w;                 w += M * 384 * 4;   // alias: ffres
  float*  val   = (float*)w;                 w += M * 256 * 4;   // alias: proj
  __bf16* ffh   = (__bf16*)w;                w += M * 1024 * 2;
  __bf16* wqv_t = (__bf16*)w;                w += (size_t)NLAYERS * 640 * 256 * 2;
  __bf16* wout_t= (__bf16*)w;                w += (size_t)NLAYERS * 256 * 256 * 2;
  __bf16* wff1_t= (__bf16*)w;                w += (size_t)NLAYERS * 1024 * 256 * 2;
  __bf16* wff2_t= (__bf16*)w;                w += (size_t)NLAYERS * 256 * 1024 * 2;
  float*  bqv   = (float*)w;                 w += (size_t)NLAYERS * 640 * 4;
  __bf16* attn_bf = qb;
  float*  proj  = val;
  float*  ffres = qproj;

  pack_qv_kernel<<<dim3(640, NLAYERS), 256, 0, stream>>>(
      W_off, W_attn, W_val, b_off, b_attn, b_val, wqv_t, bqv);
  pack_wt_kernel<<<dim3(256, NLAYERS), 256, 0, stream>>>(W_out, wout_t, 256, 256);
  pack_wt_kernel<<<dim3(1024, NLAYERS), 256, 0, stream>>>(W_ff1, wff1_t, 256, 1024);
  pack_wt_kernel<<<dim3(1024, NLAYERS), 256, 0, stream>>>(W_ff2, wff2_t, 1024, 256);

  flatten_kernel<<<MROWS, 256, 0, stream>>>(src0, pos0, src1, pos1, src2, pos2,
                                            lvl, x, pos, xb);

  const int MT = MROWS / 128;  // 168
  for (int i = 0; i < NLAYERS; ++i) {
    qb_kernel<<<MROWS / 4, 256, 0, stream>>>(x, pos, qb);
    gemm_qv_kernel<<<dim3(5, MT), 256, 0, stream>>>(
        qb, xb, wqv_t + (size_t)i * 640 * 256, bqv + i * 640, qproj, val);
    deform_kernel<<<MROWS / 4, 256, 0, stream>>>(val, qproj, attn_bf);
    gemm_bf16_kernel<0, 0><<<dim3(2, MT), 256, 0, stream>>>(
        attn_bf, wout_t + (size_t)i * 256 * 256, b_out + i * 256, proj, nullptr, 256, 256);
    add_ln_kernel<<<MROWS / 4, 256, 0, stream>>>(x, proj, ln1g + i * 256, ln1b + i * 256, x, xb);
    gemm_bf16_kernel<1, 1><<<dim3(8, MT), 256, 0, stream>>>(
        xb, wff1_t + (size_t)i * 1024 * 256, b_ff1 + i * 1024, nullptr, ffh, 1024, 256);
    gemm_bf16_kernel<0, 0><<<dim3(2, MT), 256, 0, stream>>>(
        ffh, wff2_t + (size_t)i * 256 * 1024, b_ff2 + i * 256, ffres, nullptr, 256, 1024);
    float* xdst = (i == NLAYERS - 1) ? (float*)d_out : x;
    add_ln_kernel<<<MROWS / 4, 256, 0, stream>>>(x, ffres, ln2g + i * 256, ln2b + i * 256, xdst, xb);
  }
}